// Round 1
// 466.302 us; speedup vs baseline: 1.0226x; 1.0226x over previous
//
#include <hip/hip_runtime.h>
#include <stdint.h>

typedef short bf16x8 __attribute__((ext_vector_type(8)));
typedef float f32x4 __attribute__((ext_vector_type(4)));

#define ASYNC16(g, l) __builtin_amdgcn_global_load_lds( \
    (const __attribute__((address_space(1))) unsigned int*)(g), \
    (__attribute__((address_space(3))) unsigned int*)(l), 16, 0, 0)

__device__ __forceinline__ float bf2f(short u) {
  union { unsigned int i; float f; } v;
  v.i = ((unsigned int)(unsigned short)u) << 16;
  return v.f;
}
__device__ __forceinline__ short f2bf(float f) {
  union { float f; unsigned int i; } v;
  v.f = f;
  return (short)(unsigned short)((v.i + 0x8000u) >> 16);
}
__device__ __forceinline__ float ldf(const void* p, long i, int isbf) {
  return isbf ? bf2f(((const short*)p)[i]) : ((const float*)p)[i];
}

// ---------------------------------------------------------------------------
__global__ void detect_dtype(const short* __restrict__ x, int* __restrict__ flag) {
  if (threadIdx.x == 0 && blockIdx.x == 0) {
    int cnt = 0;
    for (int i = 0; i < 128; ++i) {
      int e = (((unsigned short)x[i]) >> 7) & 0xFF;
      if (e >= 110 && e <= 136) ++cnt;
    }
    *flag = (cnt >= 120) ? 1 : 0;
  }
}

__global__ __launch_bounds__(256) void convert_x(
    const void* __restrict__ xin, short* __restrict__ xb, const int* __restrict__ flag) {
  long i = (long)blockIdx.x * 2048 + (long)threadIdx.x * 8;
  if (*flag) {
    *(bf16x8*)(xb + i) = *(const bf16x8*)((const short*)xin + i);
  } else {
    const float* xf = (const float*)xin;
    short tmp[8];
    #pragma unroll
    for (int j = 0; j < 8; ++j) tmp[j] = f2bf(xf[i + j]);
    *(bf16x8*)(xb + i) = *(bf16x8*)tmp;
  }
}

// ---------------------------------------------------------------------------
__global__ __launch_bounds__(256) void transpose_w(
    const void* __restrict__ S0, short* __restrict__ D0,
    const void* __restrict__ S1, short* __restrict__ D1,
    const void* __restrict__ S2, short* __restrict__ D2,
    const int* __restrict__ flag)
{
  int z = blockIdx.z;
  const void* S = (z == 0) ? S0 : (z == 1) ? S1 : S2;
  short* D = (z == 0) ? D0 : (z == 1) ? D1 : D2;
  int isbf = *flag;
  __shared__ short tile[32][33];
  int c0 = blockIdx.x * 32, r0 = blockIdx.y * 32;
  int tx = threadIdx.x, ty = threadIdx.y;
  #pragma unroll
  for (int i = 0; i < 4; ++i)
    tile[ty + 8*i][tx] = f2bf(ldf(S, (long)(r0 + ty + 8*i) * 2048 + c0 + tx, isbf));
  __syncthreads();
  #pragma unroll
  for (int i = 0; i < 4; ++i)
    D[(long)(c0 + ty + 8*i) * 2048 + r0 + tx] = tile[tx][ty + 8*i];
}

__global__ __launch_bounds__(256) void transpose_v(
    const short* __restrict__ Vr, short* __restrict__ Vt)
{
  __shared__ short tile[32][33];
  int bh = blockIdx.z;
  int b = bh >> 4, h = bh & 15;
  int t0 = blockIdx.x * 32, d0 = blockIdx.y * 32;
  int tx = threadIdx.x, ty = threadIdx.y;
  #pragma unroll
  for (int i = 0; i < 4; ++i)
    tile[ty + 8*i][tx] = Vr[(long)(b*2048 + t0 + ty + 8*i) * 2048 + h*128 + d0 + tx];
  __syncthreads();
  #pragma unroll
  for (int i = 0; i < 4; ++i)
    Vt[((long)bh * 128 + d0 + ty + 8*i) * 2048 + t0 + tx] = tile[tx][ty + 8*i];
}

// ---------------------------------------------------------------------------
// GEMM: BM=128, BN=256, BK=64, 512 threads (8 waves, 2x4), 64x64 per wave.
// 3-buffer LDS ring, distance-2 prefetch (tile t stages t+2), counted
// vmcnt(6) at tile boundaries (loads stay in flight across barriers),
// 2 phases/tile x 16 MFMA, setprio around MFMA clusters, XOR-octet swizzle
// folded into the global source addresses (linear global_load_lds dest).
// Race-freedom: buf[(t+2)%3] was last READ in tile t-1; all its reads are
// register-consumed before the tile-(t-1) end barrier, which precedes every
// stage issue for it, so async LDS writes can never land on live data.
// ---------------------------------------------------------------------------
template<typename OutT>
__global__ __launch_bounds__(512, 2) void gemm_bt(
    const short* __restrict__ A,
    const short* __restrict__ B0, const short* __restrict__ B1, const short* __restrict__ B2,
    OutT* __restrict__ C0, OutT* __restrict__ C1, OutT* __restrict__ C2,
    int M, int N, int K)
{
  int z = blockIdx.z;
  const short* Bt = (z == 0) ? B0 : (z == 1) ? B1 : B2;
  OutT* C = (z == 0) ? C0 : (z == 1) ? C1 : C2;

  int m0 = blockIdx.y * 128, n0 = blockIdx.x * 256;
  int tid = threadIdx.x;
  int lane = tid & 63, w = tid >> 6;
  int quad = lane >> 4, l16 = lane & 15;
  int wm = w >> 2, wn = w & 3;

  __shared__ short As[3][128*64];   // 48 KB
  __shared__ short Bs[3][256*64];   // 96 KB

  f32x4 zero4 = {0.f, 0.f, 0.f, 0.f};
  f32x4 acc[4][4];
  #pragma unroll
  for (int i = 0; i < 4; ++i)
    #pragma unroll
    for (int j = 0; j < 4; ++j) acc[i][j] = zero4;

  // staging lane constants: 8 rows x 4 octet-pairs per instruction,
  // swizzle (phys_oct = log_oct ^ (row&7)) applied on the GLOBAL side.
  int r8 = lane >> 3;
  int oct = (lane & 7) ^ r8;               // row-group bases are 0 mod 8
  const short* Ab = A  + (long)(m0 + w*16 + r8) * K + oct*8;
  const short* Bb = Bt + (long)(n0 + w*32 + r8) * K + oct*8;

  int NT = K >> 6;

  // prologue: tile 0 -> buf0, tile 1 -> buf1 (6 loads each per wave)
  #pragma unroll
  for (int u = 0; u < 2; ++u) ASYNC16(Ab + (long)u*8*K,      &As[0][(w*16 + u*8)*64]);
  #pragma unroll
  for (int u = 0; u < 4; ++u) ASYNC16(Bb + (long)u*8*K,      &Bs[0][(w*32 + u*8)*64]);
  #pragma unroll
  for (int u = 0; u < 2; ++u) ASYNC16(Ab + 64 + (long)u*8*K, &As[1][(w*16 + u*8)*64]);
  #pragma unroll
  for (int u = 0; u < 4; ++u) ASYNC16(Bb + 64 + (long)u*8*K, &Bs[1][(w*32 + u*8)*64]);
  asm volatile("s_waitcnt vmcnt(6)" ::: "memory");   // tile 0 resident, tile 1 in flight
  __builtin_amdgcn_s_barrier();

  int buf = 0, sbuf = 2;
  int po0 = ((0*4 + quad) ^ (l16 & 7)) * 8;
  int po1 = ((1*4 + quad) ^ (l16 & 7)) * 8;

  for (int t = 0; t < NT; ++t) {
    long ks = (long)(t + 2) * 64;
    bool st = (t + 2 < NT);

    // ---- phase 1 (kt = 0): 8 ds_read_b128 + 4 stage loads + 16 MFMA
    bf16x8 a0[4], b0[4];
    #pragma unroll
    for (int i = 0; i < 4; ++i)
      a0[i] = *(const bf16x8*)&As[buf][(wm*64 + i*16 + l16)*64 + po0];
    #pragma unroll
    for (int j = 0; j < 4; ++j)
      b0[j] = *(const bf16x8*)&Bs[buf][(wn*64 + j*16 + l16)*64 + po0];
    if (st) {
      #pragma unroll
      for (int u = 0; u < 2; ++u) ASYNC16(Ab + ks + (long)u*8*K, &As[sbuf][(w*16 + u*8)*64]);
      #pragma unroll
      for (int u = 0; u < 2; ++u) ASYNC16(Bb + ks + (long)u*8*K, &Bs[sbuf][(w*32 + u*8)*64]);
    }
    __builtin_amdgcn_s_barrier();
    __builtin_amdgcn_s_setprio(1);
    #pragma unroll
    for (int i = 0; i < 4; ++i)
      #pragma unroll
      for (int j = 0; j < 4; ++j)
        acc[i][j] = __builtin_amdgcn_mfma_f32_16x16x32_bf16(a0[i], b0[j], acc[i][j], 0, 0, 0);
    __builtin_amdgcn_s_setprio(0);
    __builtin_amdgcn_s_barrier();

    // ---- phase 2 (kt = 1): 8 ds_read_b128 + 2 stage loads + 16 MFMA
    bf16x8 a1[4], b1[4];
    #pragma unroll
    for (int i = 0; i < 4; ++i)
      a1[i] = *(const bf16x8*)&As[buf][(wm*64 + i*16 + l16)*64 + po1];
    #pragma unroll
    for (int j = 0; j < 4; ++j)
      b1[j] = *(const bf16x8*)&Bs[buf][(wn*64 + j*16 + l16)*64 + po1];
    if (st) {
      #pragma unroll
      for (int u = 2; u < 4; ++u) ASYNC16(Bb + ks + (long)u*8*K, &Bs[sbuf][(w*32 + u*8)*64]);
    }
    __builtin_amdgcn_s_barrier();
    __builtin_amdgcn_s_setprio(1);
    #pragma unroll
    for (int i = 0; i < 4; ++i)
      #pragma unroll
      for (int j = 0; j < 4; ++j)
        acc[i][j] = __builtin_amdgcn_mfma_f32_16x16x32_bf16(a1[i], b1[j], acc[i][j], 0, 0, 0);
    __builtin_amdgcn_s_setprio(0);
    if (t + 1 < NT) {
      // boundary: force tile t+1 resident, keep tile t+2's 6 loads in flight
      if (st) asm volatile("s_waitcnt vmcnt(6)" ::: "memory");
      else    asm volatile("s_waitcnt vmcnt(0)" ::: "memory");
      __builtin_amdgcn_s_barrier();
    }
    buf  = (buf  == 2) ? 0 : buf  + 1;
    sbuf = (sbuf == 2) ? 0 : sbuf + 1;
  }

  #pragma unroll
  for (int i = 0; i < 4; ++i)
    #pragma unroll
    for (int j = 0; j < 4; ++j) {
      int row = m0 + wm*64 + i*16 + quad*4;
      int col = n0 + wn*64 + j*16 + l16;
      #pragma unroll
      for (int r = 0; r < 4; ++r) {
        float v = acc[i][j][r];
        if constexpr (sizeof(OutT) == 4)
          C[(long)(row + r) * N + col] = v;
        else
          C[(long)(row + r) * N + col] = (OutT)f2bf(v);
      }
    }
}

// ---------------------------------------------------------------------------
__global__ __launch_bounds__(256) void pointwise(
    const short* __restrict__ xb, const void* __restrict__ ve,
    const void* __restrict__ cosb, const void* __restrict__ sinb,
    const void* __restrict__ Wg, const int* __restrict__ flag,
    short* __restrict__ Qr, short* __restrict__ Kr, short* __restrict__ Vr)
{
  int row = blockIdx.x;
  int tid = threadIdx.x;
  int isbf = *flag;
  __shared__ float xg[32];
  __shared__ float gates[16];
  if (tid < 32) xg[tid] = bf2f(xb[(long)row * 2048 + tid]);
  __syncthreads();
  if (tid < 16) {
    float g = 0.f;
    #pragma unroll
    for (int i = 0; i < 32; ++i) g += xg[i] * ldf(Wg, i*16 + tid, isbf);
    gates[tid] = 2.0f / (1.0f + __expf(-g));
  }
  __syncthreads();
  #pragma unroll
  for (int it = 0; it < 8; ++it) {
    int idx = it * 256 + tid;
    int h = idx >> 7;
    long p = (long)row * 2048 + idx;
    Vr[p] = f2bf(bf2f(Vr[p]) + gates[h] * ldf(ve, p, isbf));
  }
  int lane = tid & 63, w = tid >> 6;
  int t = row & 2047;
  #pragma unroll
  for (int it = 0; it < 8; ++it) {
    int unit = it * 4 + w;
    short* P = (unit < 16) ? Qr : Kr;
    int h = unit & 15;
    long base = (long)row * 2048 + h * 128;
    float x1 = bf2f(P[base + lane]);
    float x2 = bf2f(P[base + lane + 64]);
    float c = ldf(cosb, t*64 + lane, isbf);
    float s = ldf(sinb, t*64 + lane, isbf);
    float r1 = x1 * c + x2 * s;
    float r2 = -x1 * s + x2 * c;
    float ss = r1*r1 + r2*r2;
    #pragma unroll
    for (int off = 32; off; off >>= 1) ss += __shfl_xor(ss, off);
    float rn = rsqrtf(ss * (1.0f/128.0f) + 1e-6f);
    P[base + lane]      = f2bf(r1 * rn);
    P[base + lane + 64] = f2bf(r2 * rn);
  }
}

// ---------------------------------------------------------------------------
// Flash v3 (+ T5 setprio around MFMA clusters)
// ---------------------------------------------------------------------------
#define FL_C1 0.12751741f
#define FL_C2 16.321698f

__global__ __launch_bounds__(256) void flash(
    const short* __restrict__ Q, const short* __restrict__ K,
    const short* __restrict__ Vt, short* __restrict__ Y)
{
  int bx = blockIdx.x;
  int bh = blockIdx.y;
  int b = bh >> 4, h = bh & 15;
  int tid = threadIdx.x;
  int lane = tid & 63, w = tid >> 6;
  int quad = lane >> 4, l16 = lane & 15;

  __shared__ short Ks[2][64*128];
  __shared__ short Vts[2][128*64];
  __shared__ short Ps[4][16*72];

  int qtA = bx, qtB = 31 - bx;
  int nA = qtA + 1, nB = qtB + 1;
  int total = nA + nB;

  int kkey = tid >> 4;
  int klo  = (tid & 15) ^ (kkey & 7);
  int vd   = tid >> 3;
  int vlo  = (tid & 7) ^ (vd & 7);
  const short* Kbase = K + (long)(b*2048 + kkey) * 2048 + h*128 + klo*8;
  const short* Vbase = Vt + ((long)bh*128 + vd) * 2048 + vlo*8;

  f32x4 zero4 = {0.f, 0.f, 0.f, 0.f};
  f32x4 o[8];
  float l_i[4];
  bf16x8 qf[4];
  bf16x8 ones;
  #pragma unroll
  for (int j = 0; j < 8; ++j) ones[j] = (short)0x3F80;

  auto stage = [&](int tt, int bufp) {
    int tl = (tt < nA) ? tt : tt - nA;
    long ko = (long)tl * 64 * 2048;
    int  vo = tl * 64;
    #pragma unroll
    for (int i = 0; i < 4; ++i)
      ASYNC16(Kbase + ko + (long)i*16*2048, &Ks[bufp][(i*16 + w*4)*128]);
    #pragma unroll
    for (int i = 0; i < 4; ++i)
      ASYNC16(Vbase + vo + (long)i*32*2048, &Vts[bufp][(i*32 + w*8)*64]);
  };
  auto loadQ = [&](int qt) {
    const short* Qb = Q + (long)(b*2048 + qt*64 + w*16 + l16) * 2048 + h*128;
    #pragma unroll
    for (int kt = 0; kt < 4; ++kt)
      qf[kt] = *(const bf16x8*)(Qb + kt*32 + quad*8);
  };
  auto flushO = [&](int qt) {
    #pragma unroll
    for (int r = 0; r < 4; ++r) {
      float inv = 1.0f / fmaxf(l_i[r], 1e-30f);
      short* yp = Y + (long)(b*2048 + qt*64 + w*16 + quad*4 + r) * 2048 + h*128;
      #pragma unroll
      for (int c8 = 0; c8 < 8; ++c8)
        yp[c8*16 + l16] = f2bf(o[c8][r] * inv);
    }
  };

  #pragma unroll
  for (int c = 0; c < 8; ++c) o[c] = zero4;
  #pragma unroll
  for (int r = 0; r < 4; ++r) l_i[r] = 0.f;
  loadQ(qtA);
  stage(0, 0);

  int qt = qtA, n_seg = nA, segbase = 0;
  for (int tt = 0; tt < total; ++tt) {
    int buf = tt & 1;
    asm volatile("s_waitcnt vmcnt(0)" ::: "memory");
    __builtin_amdgcn_s_barrier();
    if (tt + 1 < total) stage(tt + 1, buf ^ 1);
    if (tt == nA) {
      flushO(qtA);
      loadQ(qtB);
      #pragma unroll
      for (int c = 0; c < 8; ++c) o[c] = zero4;
      #pragma unroll
      for (int r = 0; r < 4; ++r) l_i[r] = 0.f;
      qt = qtB; n_seg = nB; segbase = nA;
    }
    int tloc = tt - segbase;
    int kv0 = tloc * 64;

    // S = Q K^T
    f32x4 s[4];
    __builtin_amdgcn_s_setprio(1);
    #pragma unroll
    for (int c = 0; c < 4; ++c) {
      f32x4 acc = zero4;
      #pragma unroll
      for (int kt = 0; kt < 4; ++kt) {
        int po = ((kt*4 + quad) ^ (l16 & 7)) * 8;
        bf16x8 kf = *(const bf16x8*)&Ks[buf][(c*16 + l16)*128 + po];
        acc = __builtin_amdgcn_mfma_f32_16x16x32_bf16(qf[kt], kf, acc, 0, 0, 0);
      }
      s[c] = acc;
    }
    __builtin_amdgcn_s_setprio(0);

    bool domask = (tloc == n_seg - 1);
    int qgb = qt*64 + w*16 + quad*4;
    #pragma unroll
    for (int c = 0; c < 4; ++c) {
      int kg = kv0 + c*16 + l16;
      #pragma unroll
      for (int r = 0; r < 4; ++r) {
        float t = s[c][r] * FL_C1 - FL_C2;
        if (domask && kg > qgb + r) t = -1000.0f;
        float pv = exp2f(t);
        Ps[w][(quad*4 + r)*72 + c*16 + l16] = f2bf(pv);
      }
    }
    asm volatile("s_waitcnt lgkmcnt(0)" ::: "memory");
    bf16x8 pa0 = *(const bf16x8*)&Ps[w][l16*72 + quad*8];
    bf16x8 pa1 = *(const bf16x8*)&Ps[w][l16*72 + 32 + quad*8];

    __builtin_amdgcn_s_setprio(1);
    f32x4 racc = __builtin_amdgcn_mfma_f32_16x16x32_bf16(pa0, ones, zero4, 0, 0, 0);
    racc = __builtin_amdgcn_mfma_f32_16x16x32_bf16(pa1, ones, racc, 0, 0, 0);
    #pragma unroll
    for (int r = 0; r < 4; ++r) l_i[r] += racc[r];

    #pragma unroll
    for (int c8 = 0; c8 < 8; ++c8) {
      int po0 = ((0*4 + quad) ^ (l16 & 7)) * 8;
      int po1 = ((1*4 + quad) ^ (l16 & 7)) * 8;
      bf16x8 v0 = *(const bf16x8*)&Vts[buf][(c8*16 + l16)*64 + po0];
      bf16x8 v1 = *(const bf16x8*)&Vts[buf][(c8*16 + l16)*64 + po1];
      o[c8] = __builtin_amdgcn_mfma_f32_16x16x32_bf16(pa0, v0, o[c8], 0, 0, 0);
      o[c8] = __builtin_amdgcn_mfma_f32_16x16x32_bf16(pa1, v1, o[c8], 0, 0, 0);
    }
    __builtin_amdgcn_s_setprio(0);
  }
  flushO(qtB);
}

// ---------------------------------------------------------------------------
extern "C" void kernel_launch(void* const* d_in, const int* in_sizes, int n_in,
                              void* d_out, int out_size, void* d_ws, size_t ws_size,
                              hipStream_t stream) {
  const void* x    = d_in[0];
  const void* ve   = d_in[1];
  const void* cosb = d_in[2];
  const void* sinb = d_in[3];
  const void* Wq   = d_in[4];
  const void* Wk   = d_in[5];
  const void* Wv   = d_in[6];
  const void* Wg   = d_in[7];
  const void* Wp   = d_in[8];
  float* out = (float*)d_out;

  int*   flag = (int*)d_ws;
  short* base = (short*)d_ws + 256;
  short* wt0 = base;                       // 4M: Wq^T, then Wp^T
  short* wtk = base + 4194304L;            // 4M: Wk^T (dead after QKV gemm)
  short* wtv = base + 8388608L;            // 4M: Wv^T (dead after QKV gemm)
  short* Vt  = base + 4194304L;            // 8M: aliases wtk+wtv
  short* xb  = base + 12582912L;           // 8M: bf16 x (dead after pointwise)
  short* Y   = base + 12582912L;           // 8M: aliases xb
  short* Qr  = base + 20971520L;           // 8M
  short* Kr  = base + 29360128L;           // 8M
  short* Vr  = base + 37748736L;           // 8M

  detect_dtype<<<1, 64, 0, stream>>>((const short*)x, flag);
  convert_x<<<4096, 256, 0, stream>>>(x, xb, flag);
  transpose_w<<<dim3(64, 64, 3), dim3(32, 8), 0, stream>>>(Wq, wt0, Wk, wtk, Wv, wtv, flag);
  gemm_bt<short><<<dim3(8, 32, 3), 512, 0, stream>>>(xb, wt0, wtk, wtv, Qr, Kr, Vr, 4096, 2048, 2048);
  transpose_w<<<dim3(64, 64, 1), dim3(32, 8), 0, stream>>>(Wp, wt0, Wp, wt0, Wp, wt0, flag);
  pointwise<<<dim3(4096), 256, 0, stream>>>(xb, ve, cosb, sinb, Wg, flag, Qr, Kr, Vr);
  transpose_v<<<dim3(64, 4, 32), dim3(32, 8), 0, stream>>>(Vr, Vt);
  flash<<<dim3(16, 32), 256, 0, stream>>>(Qr, Kr, Vt, Y);
  gemm_bt<float><<<dim3(8, 32, 1), 512, 0, stream>>>(Y, wt0, wt0, wt0, out, out, out, 4096, 2048, 2048);
}